// Round 1
// baseline (356.871 us; speedup 1.0000x reference)
//
#include <hip/hip_runtime.h>

typedef unsigned short ushort_t;
typedef __attribute__((ext_vector_type(8))) short short8;
typedef __attribute__((ext_vector_type(8))) unsigned short ushort8;
typedef __attribute__((ext_vector_type(4))) unsigned short ushort4v;
typedef __attribute__((ext_vector_type(2))) unsigned short ushort2v;
typedef __attribute__((ext_vector_type(4))) float f32x4;
typedef __attribute__((ext_vector_type(4))) float float4v;

__device__ __forceinline__ float bf2f(ushort_t u) {
  return __uint_as_float(((unsigned)u) << 16);
}
__device__ __forceinline__ ushort_t f2bf(float f) {
  unsigned u = __float_as_uint(f);
  u += 0x7fffu + ((u >> 16) & 1u);   // RNE; inputs never NaN
  return (ushort_t)(u >> 16);
}

// ---------------- alpha = mean(|w|) + 1e-8 (two-stage, deterministic) ----------------
__global__ void k_abs_partial(const float* __restrict__ w1, const float* __restrict__ w2,
                              const float* __restrict__ w3, const float* __restrict__ w4,
                              float* __restrict__ apart) {
  int wy = blockIdx.y;
  const float* w; int n;
  if (wy == 0)      { w = w1; n = 1024 * 784; }
  else if (wy == 1) { w = w2; n = 512 * 1024; }
  else if (wy == 2) { w = w3; n = 256 * 512; }
  else              { w = w4; n = 10 * 256; }
  float s = 0.f;
  for (int i = blockIdx.x * 256 + threadIdx.x; i < n; i += 64 * 256)
    s += fabsf(w[i]);
  __shared__ float red[256];
  red[threadIdx.x] = s;
  __syncthreads();
  for (int st = 128; st > 0; st >>= 1) {
    if (threadIdx.x < st) red[threadIdx.x] += red[threadIdx.x + st];
    __syncthreads();
  }
  if (threadIdx.x == 0) apart[wy * 64 + blockIdx.x] = red[0];
}

__global__ void k_alpha_fin(const float* __restrict__ apart, float* __restrict__ alphas) {
  int wid = threadIdx.x >> 6, lane = threadIdx.x & 63;
  float v = apart[wid * 64 + lane];
  #pragma unroll
  for (int off = 32; off > 0; off >>= 1) v += __shfl_xor(v, off);
  if (lane == 0) {
    float inv;
    if (wid == 0)      inv = 1.f / (1024.f * 784.f);
    else if (wid == 1) inv = 1.f / (512.f * 1024.f);
    else if (wid == 2) inv = 1.f / (256.f * 512.f);
    else               inv = 1.f / 2560.f;
    alphas[wid] = v * inv + 1e-8f;
  }
}

// ---------------- ternary quantize -> bf16 {-1,0,1}, alpha factored out ----------------
__global__ void k_quantize(const float* __restrict__ w1, const float* __restrict__ w2,
                           const float* __restrict__ w3, const float* __restrict__ w4,
                           ushort_t* __restrict__ q1, ushort_t* __restrict__ q2,
                           ushort_t* __restrict__ q3, ushort_t* __restrict__ q4,
                           const float* __restrict__ alphas) {
  int wy = blockIdx.y;
  const float* w; ushort_t* q; int R, K, Kp;
  if (wy == 0)      { w = w1; q = q1; R = 1024; K = 784;  Kp = 832;  }
  else if (wy == 1) { w = w2; q = q2; R = 512;  K = 1024; Kp = 1024; }
  else if (wy == 2) { w = w3; q = q3; R = 256;  K = 512;  Kp = 512;  }
  else              { w = w4; q = q4; R = 10;   K = 256;  Kp = 256;  }
  float a = alphas[wy];
  int total = R * Kp;
  for (int i = blockIdx.x * 256 + threadIdx.x; i < total; i += gridDim.x * 256) {
    int r = i / Kp, k = i - r * Kp;
    float v = 0.f;
    if (k < K) {
      float t = rintf(w[r * K + k] / a);   // rintf = RNE, matches jnp.round
      v = fminf(1.f, fmaxf(-1.f, t));
    }
    q[i] = f2bf(v);   // exact for {-1,0,1}
  }
}

// ---------------- x (f32, 32768x784) -> bf16 padded to 832 ----------------
__global__ void k_convert_x(const float* __restrict__ x, ushort_t* __restrict__ xq) {
  int idx = blockIdx.x * 256 + threadIdx.x;   // 32768*104 threads, 8 elems each
  int r = idx / 104;
  int c8 = idx - r * 104;
  int k0 = c8 << 3;
  ushort8 o;
  if (k0 < 784) {   // 784 % 8 == 0, so full chunks only
    const float4v* p = (const float4v*)(x + (size_t)r * 784 + k0);
    float4v v0 = p[0], v1 = p[1];
    o[0] = f2bf(v0[0]); o[1] = f2bf(v0[1]); o[2] = f2bf(v0[2]); o[3] = f2bf(v0[3]);
    o[4] = f2bf(v1[0]); o[5] = f2bf(v1[1]); o[6] = f2bf(v1[2]); o[7] = f2bf(v1[3]);
  } else {
    #pragma unroll
    for (int j = 0; j < 8; ++j) o[j] = 0;
  }
  *(ushort8*)(xq + (size_t)r * 832 + k0) = o;
}

// ---------------- 128x128-tile bf16 MFMA GEMM, C = alpha * (A @ B^T), bf16 out -------
// A: [32768 x K] bf16, B: [N x K] bf16 (ternary), C: [32768 x N] bf16.
// 256 threads = 4 waves (2x2), each wave 64x64 (4x4 frags of 16x16x32). BK=64.
// Register staging (safe-compile baseline; global_load_lds next round).
__global__ __launch_bounds__(256, 2) void k_gemm_bt(
    const ushort_t* __restrict__ A, const ushort_t* __restrict__ Bw,
    ushort_t* __restrict__ C, const float* __restrict__ alphas, int layer,
    int N, int K) {
  __shared__ ushort_t As[8192];   // [128][64] linear
  __shared__ ushort_t Bs[8192];
  const int tid = threadIdx.x;
  const int lane = tid & 63;
  const int wr = (tid >> 7) & 1;
  const int wc = (tid >> 6) & 1;
  const int l15 = lane & 15, l4 = lane >> 4;
  const int row0 = blockIdx.y << 7, col0 = blockIdx.x << 7;

  f32x4 acc[4][4];
  #pragma unroll
  for (int m = 0; m < 4; ++m)
    #pragma unroll
    for (int n = 0; n < 4; ++n) acc[m][n] = (f32x4){0.f, 0.f, 0.f, 0.f};

  // staging geometry: thread covers 4 chunks of 16B for A and B each
  const int srow = tid >> 3;            // 0..31
  const int sk = (tid & 7) << 3;        // 0,8,...,56
  const ushort_t* Aptr = A + (size_t)(row0 + srow) * K + sk;
  const ushort_t* Bptr = Bw + (size_t)(col0 + srow) * K + sk;
  const size_t rstride = (size_t)32 * K;
  const int swoff = srow * 64 + sk;

  ushort8 ra[4], rb[4];
  #pragma unroll
  for (int c = 0; c < 4; ++c) {
    ra[c] = *(const ushort8*)(Aptr + c * rstride);
    rb[c] = *(const ushort8*)(Bptr + c * rstride);
  }

  const int nk = K >> 6;
  for (int kt = 0; kt < nk; ++kt) {
    __syncthreads();                    // previous compute done with LDS
    #pragma unroll
    for (int c = 0; c < 4; ++c) {
      *(ushort8*)(As + swoff + c * 2048) = ra[c];
      *(ushort8*)(Bs + swoff + c * 2048) = rb[c];
    }
    __syncthreads();
    if (kt + 1 < nk) {                  // prefetch next tile; overlaps MFMA below
      const ushort_t* An = Aptr + (size_t)(kt + 1) * 64;
      const ushort_t* Bn = Bptr + (size_t)(kt + 1) * 64;
      #pragma unroll
      for (int c = 0; c < 4; ++c) {
        ra[c] = *(const ushort8*)(An + c * rstride);
        rb[c] = *(const ushort8*)(Bn + c * rstride);
      }
    }
    #pragma unroll
    for (int ks = 0; ks < 2; ++ks) {
      short8 af[4], bf[4];
      #pragma unroll
      for (int m = 0; m < 4; ++m)
        af[m] = *(const short8*)(As + (wr * 64 + m * 16 + l15) * 64 + ks * 32 + l4 * 8);
      #pragma unroll
      for (int n = 0; n < 4; ++n)
        bf[n] = *(const short8*)(Bs + (wc * 64 + n * 16 + l15) * 64 + ks * 32 + l4 * 8);
      #pragma unroll
      for (int m = 0; m < 4; ++m)
        #pragma unroll
        for (int n = 0; n < 4; ++n)
          acc[m][n] = __builtin_amdgcn_mfma_f32_16x16x32_bf16(af[m], bf[n], acc[m][n], 0, 0, 0);
    }
  }

  const float alpha = alphas[layer];
  #pragma unroll
  for (int m = 0; m < 4; ++m) {
    const int rbase = row0 + wr * 64 + m * 16 + l4 * 4;
    #pragma unroll
    for (int n = 0; n < 4; ++n) {
      const int col = col0 + wc * 64 + n * 16 + l15;
      #pragma unroll
      for (int r = 0; r < 4; ++r)
        C[(size_t)(rbase + r) * N + col] = f2bf(acc[m][n][r] * alpha);
    }
  }
}

// ---------------- BN column stats (2-stage deterministic) ----------------
template <int N>
__global__ void k_bn_stats(const ushort_t* __restrict__ Y, float* __restrict__ psum,
                           float* __restrict__ psq) {
  constexpr int F = N / 256;
  int b = blockIdx.x, t = threadIdx.x;   // 256 blocks x 128 rows
  float s[F], q[F];
  #pragma unroll
  for (int j = 0; j < F; ++j) { s[j] = 0.f; q[j] = 0.f; }
  const ushort_t* p = Y + (size_t)b * 128 * N + t * F;
  for (int r = 0; r < 128; ++r) {
    if constexpr (F == 4) {
      ushort4v v = *(const ushort4v*)p;
      #pragma unroll
      for (int j = 0; j < 4; ++j) { float f = bf2f(v[j]); s[j] += f; q[j] += f * f; }
    } else if constexpr (F == 2) {
      ushort2v v = *(const ushort2v*)p;
      #pragma unroll
      for (int j = 0; j < 2; ++j) { float f = bf2f(v[j]); s[j] += f; q[j] += f * f; }
    } else {
      float f = bf2f(*p); s[0] += f; q[0] += f * f;
    }
    p += N;
  }
  #pragma unroll
  for (int j = 0; j < F; ++j) {
    psum[(size_t)b * N + t * F + j] = s[j];
    psq [(size_t)b * N + t * F + j] = q[j];
  }
}

__global__ void k_bn_fin(const float* __restrict__ psum, const float* __restrict__ psq,
                         const float* __restrict__ g, const float* __restrict__ bb,
                         int N, float* __restrict__ SB) {
  int f = blockIdx.x * 256 + threadIdx.x;
  float s = 0.f, q = 0.f;
  for (int b2 = 0; b2 < 256; ++b2) {
    s += psum[(size_t)b2 * N + f];
    q += psq [(size_t)b2 * N + f];
  }
  float mean = s * (1.f / 32768.f);
  float var  = q * (1.f / 32768.f) - mean * mean;   // biased, matches torch/jnp
  float Sv = g[f] / sqrtf(var + 1e-5f);
  float Bv = bb[f] - mean * Sv;
  SB[f] = Sv;
  SB[N + f] = Bv;
}

// ---------------- in-place normalize + ReLU (bf16) ----------------
__global__ void k_bn_norm(ushort_t* __restrict__ Y, const float* __restrict__ SB, int N) {
  size_t e0 = ((size_t)blockIdx.x * 256 + threadIdx.x) * 8;
  int f0 = (int)(e0 & (size_t)(N - 1));
  ushort8 v = *(const ushort8*)(Y + e0);
  const float4v* Sp = (const float4v*)(SB + f0);
  const float4v* Bp = (const float4v*)(SB + N + f0);
  float4v S0 = Sp[0], S1 = Sp[1], B0 = Bp[0], B1 = Bp[1];
  ushort8 o;
  #pragma unroll
  for (int j = 0; j < 4; ++j) {
    float h = fmaxf(bf2f(v[j]) * S0[j] + B0[j], 0.f);
    o[j] = f2bf(h);
  }
  #pragma unroll
  for (int j = 0; j < 4; ++j) {
    float h = fmaxf(bf2f(v[4 + j]) * S1[j] + B1[j], 0.f);
    o[4 + j] = f2bf(h);
  }
  *(ushort8*)(Y + e0) = o;
}

// ---------------- final layer: out[32768 x 10] = alpha4 * (h3 @ t4^T), f32 ----------
__global__ void k_final(const ushort_t* __restrict__ H, const ushort_t* __restrict__ W4,
                        const float* __restrict__ alphas, float* __restrict__ out) {
  int lane = threadIdx.x & 63, wid = threadIdx.x >> 6;
  int row = blockIdx.x * 4 + wid;
  float a4 = alphas[3];
  ushort4v hv = *(const ushort4v*)(H + (size_t)row * 256 + lane * 4);
  float hf[4];
  #pragma unroll
  for (int j = 0; j < 4; ++j) hf[j] = bf2f(hv[j]);
  float acc[10];
  #pragma unroll
  for (int c = 0; c < 10; ++c) {
    ushort4v wv = *(const ushort4v*)(W4 + c * 256 + lane * 4);
    acc[c] = hf[0] * bf2f(wv[0]) + hf[1] * bf2f(wv[1]) +
             hf[2] * bf2f(wv[2]) + hf[3] * bf2f(wv[3]);
  }
  #pragma unroll
  for (int c = 0; c < 10; ++c) {
    #pragma unroll
    for (int off = 32; off > 0; off >>= 1) acc[c] += __shfl_xor(acc[c], off);
  }
  if (lane < 10) {
    float v = 0.f;
    #pragma unroll
    for (int c = 0; c < 10; ++c)
      if (lane == c) v = acc[c];
    out[(size_t)row * 10 + lane] = v * a4;
  }
}

// =====================================================================================
extern "C" void kernel_launch(void* const* d_in, const int* in_sizes, int n_in,
                              void* d_out, int out_size, void* d_ws, size_t ws_size,
                              hipStream_t stream) {
  const float* x  = (const float*)d_in[0];
  const float* w1 = (const float*)d_in[1];
  const float* w2 = (const float*)d_in[2];
  const float* w3 = (const float*)d_in[3];
  const float* w4 = (const float*)d_in[4];
  const float* g1 = (const float*)d_in[5];
  const float* b1 = (const float*)d_in[6];
  const float* g2 = (const float*)d_in[7];
  const float* b2 = (const float*)d_in[8];
  const float* g3 = (const float*)d_in[9];
  const float* b3 = (const float*)d_in[10];
  float* out = (float*)d_out;

  // workspace layout (121 MB total; xq region aliased for y2/y3 after xq is dead)
  char* ws = (char*)d_ws;
  float* alphas   = (float*)(ws + 0);                    // 4 f32
  float* apart    = (float*)(ws + 256);                  // 4*64 f32
  float* psum     = (float*)(ws + 1536);                 // 256*1024 f32 (1 MB)
  float* psq      = (float*)(ws + 1050112);              // 1 MB
  float* SB       = (float*)(ws + 2098688);              // 2*1024 f32
  ushort_t* wq1   = (ushort_t*)(ws + 2106880);           // 1024x832
  ushort_t* wq2   = (ushort_t*)(ws + 3810816);           // 512x1024
  ushort_t* wq3   = (ushort_t*)(ws + 4859392);           // 256x512
  ushort_t* wq4   = (ushort_t*)(ws + 5121536);           // 10x256
  ushort_t* xq    = (ushort_t*)(ws + 5126656);           // 32768x832 (54.5 MB)
  ushort_t* y2    = xq;                                  // alias: xq dead after GEMM1
  ushort_t* y3    = (ushort_t*)(ws + 5126656 + 33554432);
  ushort_t* y1    = (ushort_t*)(ws + 59652608);          // 32768x1024 (67 MB)

  dim3 blk(256);

  k_abs_partial<<<dim3(64, 4), blk, 0, stream>>>(w1, w2, w3, w4, apart);
  k_alpha_fin<<<1, blk, 0, stream>>>(apart, alphas);
  k_quantize<<<dim3(512, 4), blk, 0, stream>>>(w1, w2, w3, w4, wq1, wq2, wq3, wq4, alphas);
  k_convert_x<<<13312, blk, 0, stream>>>(x, xq);

  // layer 1: 32768 x 1024, K = 832 (padded)
  k_gemm_bt<<<dim3(8, 256), blk, 0, stream>>>(xq, wq1, y1, alphas, 0, 1024, 832);
  k_bn_stats<1024><<<256, blk, 0, stream>>>(y1, psum, psq);
  k_bn_fin<<<4, blk, 0, stream>>>(psum, psq, g1, b1, 1024, SB);
  k_bn_norm<<<16384, blk, 0, stream>>>(y1, SB, 1024);

  // layer 2: 32768 x 512, K = 1024
  k_gemm_bt<<<dim3(4, 256), blk, 0, stream>>>(y1, wq2, y2, alphas, 1, 512, 1024);
  k_bn_stats<512><<<256, blk, 0, stream>>>(y2, psum, psq);
  k_bn_fin<<<2, blk, 0, stream>>>(psum, psq, g2, b2, 512, SB);
  k_bn_norm<<<8192, blk, 0, stream>>>(y2, SB, 512);

  // layer 3: 32768 x 256, K = 512
  k_gemm_bt<<<dim3(2, 256), blk, 0, stream>>>(y2, wq3, y3, alphas, 2, 256, 512);
  k_bn_stats<256><<<256, blk, 0, stream>>>(y3, psum, psq);
  k_bn_fin<<<1, blk, 0, stream>>>(psum, psq, g3, b3, 256, SB);
  k_bn_norm<<<4096, blk, 0, stream>>>(y3, SB, 256);

  // layer 4: 32768 x 10, K = 256 (memory-bound GEMV)
  k_final<<<8192, blk, 0, stream>>>(y3, wq4, alphas, out);
}

// Round 2
// 314.756 us; speedup vs baseline: 1.1338x; 1.1338x over previous
//
#include <hip/hip_runtime.h>

typedef unsigned short ushort_t;
typedef __attribute__((ext_vector_type(8))) short short8;
typedef __attribute__((ext_vector_type(8))) unsigned short ushort8;
typedef __attribute__((ext_vector_type(4))) unsigned short ushort4v;
typedef __attribute__((ext_vector_type(2))) unsigned short ushort2v;
typedef __attribute__((ext_vector_type(4))) float f32x4;
typedef __attribute__((ext_vector_type(4))) float float4v;

__device__ __forceinline__ float bf2f(ushort_t u) {
  return __uint_as_float(((unsigned)u) << 16);
}
__device__ __forceinline__ ushort_t f2bf(float f) {
  unsigned u = __float_as_uint(f);
  u += 0x7fffu + ((u >> 16) & 1u);   // RNE; inputs never NaN
  return (ushort_t)(u >> 16);
}

// async global->LDS, 16B per lane. LDS dest is wave-uniform base + lane*16.
__device__ __forceinline__ void gload16(ushort_t* lds, const ushort_t* g) {
  __builtin_amdgcn_global_load_lds(
      (const __attribute__((address_space(1))) unsigned int*)g,
      (__attribute__((address_space(3))) unsigned int*)lds, 16, 0, 0);
}

// ---------------- alpha = mean(|w|) + 1e-8 (two-stage, deterministic) ----------------
__global__ void k_abs_partial(const float* __restrict__ w1, const float* __restrict__ w2,
                              const float* __restrict__ w3, const float* __restrict__ w4,
                              float* __restrict__ apart) {
  int wy = blockIdx.y;
  const float* w; int n;
  if (wy == 0)      { w = w1; n = 1024 * 784; }
  else if (wy == 1) { w = w2; n = 512 * 1024; }
  else if (wy == 2) { w = w3; n = 256 * 512; }
  else              { w = w4; n = 10 * 256; }
  float s = 0.f;
  for (int i = blockIdx.x * 256 + threadIdx.x; i < n; i += 64 * 256)
    s += fabsf(w[i]);
  __shared__ float red[256];
  red[threadIdx.x] = s;
  __syncthreads();
  for (int st = 128; st > 0; st >>= 1) {
    if (threadIdx.x < st) red[threadIdx.x] += red[threadIdx.x + st];
    __syncthreads();
  }
  if (threadIdx.x == 0) apart[wy * 64 + blockIdx.x] = red[0];
}

__global__ void k_alpha_fin(const float* __restrict__ apart, float* __restrict__ alphas) {
  int wid = threadIdx.x >> 6, lane = threadIdx.x & 63;
  float v = apart[wid * 64 + lane];
  #pragma unroll
  for (int off = 32; off > 0; off >>= 1) v += __shfl_xor(v, off);
  if (lane == 0) {
    float inv;
    if (wid == 0)      inv = 1.f / (1024.f * 784.f);
    else if (wid == 1) inv = 1.f / (512.f * 1024.f);
    else if (wid == 2) inv = 1.f / (256.f * 512.f);
    else               inv = 1.f / 2560.f;
    alphas[wid] = v * inv + 1e-8f;
  }
}

// ---------------- ternary quantize -> bf16 {-1,0,1}, alpha factored out ----------------
__global__ void k_quantize(const float* __restrict__ w1, const float* __restrict__ w2,
                           const float* __restrict__ w3, const float* __restrict__ w4,
                           ushort_t* __restrict__ q1, ushort_t* __restrict__ q2,
                           ushort_t* __restrict__ q3, ushort_t* __restrict__ q4,
                           const float* __restrict__ alphas) {
  int wy = blockIdx.y;
  const float* w; ushort_t* q; int R, K, Kp;
  if (wy == 0)      { w = w1; q = q1; R = 1024; K = 784;  Kp = 832;  }
  else if (wy == 1) { w = w2; q = q2; R = 512;  K = 1024; Kp = 1024; }
  else if (wy == 2) { w = w3; q = q3; R = 256;  K = 512;  Kp = 512;  }
  else              { w = w4; q = q4; R = 10;   K = 256;  Kp = 256;  }
  float a = alphas[wy];
  int total = R * Kp;
  for (int i = blockIdx.x * 256 + threadIdx.x; i < total; i += gridDim.x * 256) {
    int r = i / Kp, k = i - r * Kp;
    float v = 0.f;
    if (k < K) {
      float t = rintf(w[r * K + k] / a);   // rintf = RNE, matches jnp.round
      v = fminf(1.f, fmaxf(-1.f, t));
    }
    q[i] = f2bf(v);   // exact for {-1,0,1}
  }
}

// ---------------- x (f32, 32768x784) -> bf16 padded to 832 ----------------
__global__ void k_convert_x(const float* __restrict__ x, ushort_t* __restrict__ xq) {
  int idx = blockIdx.x * 256 + threadIdx.x;   // 32768*104 threads, 8 elems each
  int r = idx / 104;
  int c8 = idx - r * 104;
  int k0 = c8 << 3;
  ushort8 o;
  if (k0 < 784) {   // 784 % 8 == 0, so full chunks only
    const float4v* p = (const float4v*)(x + (size_t)r * 784 + k0);
    float4v v0 = p[0], v1 = p[1];
    o[0] = f2bf(v0[0]); o[1] = f2bf(v0[1]); o[2] = f2bf(v0[2]); o[3] = f2bf(v0[3]);
    o[4] = f2bf(v1[0]); o[5] = f2bf(v1[1]); o[6] = f2bf(v1[2]); o[7] = f2bf(v1[3]);
  } else {
    #pragma unroll
    for (int j = 0; j < 8; ++j) o[j] = 0;
  }
  *(ushort8*)(xq + (size_t)r * 832 + k0) = o;
}

// ---------------- 128x128-tile bf16 MFMA GEMM, C = alpha * (A @ B^T), bf16 out -------
// A: [32768 x K] bf16, B: [N x K] bf16 (ternary), C: [32768 x N] bf16.
// 256 threads = 4 waves (2x2), each wave 64x64 (4x4 frags of 16x16x32). BK=64.
// m97 structure: global_load_lds width=16 staging, 2 barriers/K-step.
// 1D grid + bijective XCD swizzle (nwg % 8 == 0 for all our shapes): each XCD
// gets a contiguous chunk of row-panels -> A fetched once chip-wide.
__global__ __launch_bounds__(256, 3) void k_gemm_bt(
    const ushort_t* __restrict__ A, const ushort_t* __restrict__ Bw,
    ushort_t* __restrict__ C, const float* __restrict__ alphas, int layer,
    int N, int K, int nbxl) {
  __shared__ ushort_t As[8192];   // [128][64] linear
  __shared__ ushort_t Bs[8192];
  const int tid = threadIdx.x;
  const int lane = tid & 63;
  const int wv = tid >> 6;
  const int wr = (tid >> 7) & 1;
  const int wc = (tid >> 6) & 1;
  const int l15 = lane & 15, l4 = lane >> 4;

  const int cpx = gridDim.x >> 3;                         // chunk per XCD
  const int orig = (blockIdx.x & 7) * cpx + (blockIdx.x >> 3);
  const int colt = orig & ((1 << nbxl) - 1);
  const int rowt = orig >> nbxl;                          // consecutive origs share rowt
  const int row0 = rowt << 7, col0 = colt << 7;

  f32x4 acc[4][4];
  #pragma unroll
  for (int m = 0; m < 4; ++m)
    #pragma unroll
    for (int n = 0; n < 4; ++n) acc[m][n] = (f32x4){0.f, 0.f, 0.f, 0.f};

  // staging: wave wv owns rows [wv*32, wv*32+32); 4 issues x (8 rows x 64 cols)
  const int srow = lane >> 3;            // 0..7
  const int sk = (lane & 7) << 3;        // 0,8,...,56
  const ushort_t* Ag = A + (size_t)(row0 + wv * 32 + srow) * K + sk;
  const ushort_t* Bg = Bw + (size_t)(col0 + wv * 32 + srow) * K + sk;
  ushort_t* Asw = As + wv * 32 * 64;     // wave-uniform LDS bases
  ushort_t* Bsw = Bs + wv * 32 * 64;
  const size_t r8 = (size_t)8 * K;

  const int nk = K >> 6;
  for (int kt = 0; kt < nk; ++kt) {
    __syncthreads();                     // previous compute done with LDS
    const ushort_t* Agk = Ag + kt * 64;
    const ushort_t* Bgk = Bg + kt * 64;
    #pragma unroll
    for (int c = 0; c < 4; ++c) {
      gload16(Asw + c * 512, Agk + c * r8);
      gload16(Bsw + c * 512, Bgk + c * r8);
    }
    __syncthreads();                     // vmcnt(0) drain -> tile resident
    #pragma unroll
    for (int ks = 0; ks < 2; ++ks) {
      short8 af[4], bf[4];
      #pragma unroll
      for (int m = 0; m < 4; ++m)
        af[m] = *(const short8*)(As + (wr * 64 + m * 16 + l15) * 64 + ks * 32 + l4 * 8);
      #pragma unroll
      for (int n = 0; n < 4; ++n)
        bf[n] = *(const short8*)(Bs + (wc * 64 + n * 16 + l15) * 64 + ks * 32 + l4 * 8);
      #pragma unroll
      for (int m = 0; m < 4; ++m)
        #pragma unroll
        for (int n = 0; n < 4; ++n)
          acc[m][n] = __builtin_amdgcn_mfma_f32_16x16x32_bf16(af[m], bf[n], acc[m][n], 0, 0, 0);
    }
  }

  const float alpha = alphas[layer];
  #pragma unroll
  for (int m = 0; m < 4; ++m) {
    const int rbase = row0 + wr * 64 + m * 16 + l4 * 4;
    #pragma unroll
    for (int n = 0; n < 4; ++n) {
      const int col = col0 + wc * 64 + n * 16 + l15;
      #pragma unroll
      for (int r = 0; r < 4; ++r)
        C[(size_t)(rbase + r) * N + col] = f2bf(acc[m][n][r] * alpha);
    }
  }
}

// ---------------- BN column stats (2-stage deterministic, 64 partials) ----------------
template <int N>
__global__ void k_bn_stats(const ushort_t* __restrict__ Y, float* __restrict__ psum,
                           float* __restrict__ psq) {
  constexpr int F = N / 256;
  int b = blockIdx.x, t = threadIdx.x;   // 64 blocks x 512 rows
  float s[F], q[F];
  #pragma unroll
  for (int j = 0; j < F; ++j) { s[j] = 0.f; q[j] = 0.f; }
  const ushort_t* p = Y + (size_t)b * 512 * N + t * F;
  for (int r = 0; r < 512; ++r) {
    if constexpr (F == 4) {
      ushort4v v = *(const ushort4v*)p;
      #pragma unroll
      for (int j = 0; j < 4; ++j) { float f = bf2f(v[j]); s[j] += f; q[j] += f * f; }
    } else if constexpr (F == 2) {
      ushort2v v = *(const ushort2v*)p;
      #pragma unroll
      for (int j = 0; j < 2; ++j) { float f = bf2f(v[j]); s[j] += f; q[j] += f * f; }
    } else {
      float f = bf2f(*p); s[0] += f; q[0] += f * f;
    }
    p += N;
  }
  #pragma unroll
  for (int j = 0; j < F; ++j) {
    psum[(size_t)b * N + t * F + j] = s[j];
    psq [(size_t)b * N + t * F + j] = q[j];
  }
}

__global__ void k_bn_fin(const float* __restrict__ psum, const float* __restrict__ psq,
                         const float* __restrict__ g, const float* __restrict__ bb,
                         int N, float* __restrict__ SB) {
  int f = blockIdx.x * 256 + threadIdx.x;
  float s = 0.f, q = 0.f;
  for (int b2 = 0; b2 < 64; ++b2) {
    s += psum[(size_t)b2 * N + f];
    q += psq [(size_t)b2 * N + f];
  }
  float mean = s * (1.f / 32768.f);
  float var  = q * (1.f / 32768.f) - mean * mean;   // biased, matches torch/jnp
  float Sv = g[f] / sqrtf(var + 1e-5f);
  float Bv = bb[f] - mean * Sv;
  SB[f] = Sv;
  SB[N + f] = Bv;
}

// ---------------- in-place normalize + ReLU (bf16) ----------------
__global__ void k_bn_norm(ushort_t* __restrict__ Y, const float* __restrict__ SB, int N) {
  size_t e0 = ((size_t)blockIdx.x * 256 + threadIdx.x) * 8;
  int f0 = (int)(e0 & (size_t)(N - 1));
  ushort8 v = *(const ushort8*)(Y + e0);
  const float4v* Sp = (const float4v*)(SB + f0);
  const float4v* Bp = (const float4v*)(SB + N + f0);
  float4v S0 = Sp[0], S1 = Sp[1], B0 = Bp[0], B1 = Bp[1];
  ushort8 o;
  #pragma unroll
  for (int j = 0; j < 4; ++j) {
    float h = fmaxf(bf2f(v[j]) * S0[j] + B0[j], 0.f);
    o[j] = f2bf(h);
  }
  #pragma unroll
  for (int j = 0; j < 4; ++j) {
    float h = fmaxf(bf2f(v[4 + j]) * S1[j] + B1[j], 0.f);
    o[4 + j] = f2bf(h);
  }
  *(ushort8*)(Y + e0) = o;
}

// -------- final layer: out = alpha4 * (relu(bn3(y3)) @ t4^T); norm3 fused in --------
__global__ void k_final(const ushort_t* __restrict__ H, const ushort_t* __restrict__ W4,
                        const float* __restrict__ alphas, const float* __restrict__ SB,
                        float* __restrict__ out) {
  int lane = threadIdx.x & 63, wid = threadIdx.x >> 6;
  int row = blockIdx.x * 4 + wid;
  float a4 = alphas[3];
  ushort4v hv = *(const ushort4v*)(H + (size_t)row * 256 + lane * 4);
  float4v S = *(const float4v*)(SB + lane * 4);
  float4v Bv = *(const float4v*)(SB + 256 + lane * 4);
  float hf[4];
  #pragma unroll
  for (int j = 0; j < 4; ++j)
    hf[j] = fmaxf(bf2f(hv[j]) * S[j] + Bv[j], 0.f);   // BN3 + ReLU fused
  float acc[10];
  #pragma unroll
  for (int c = 0; c < 10; ++c) {
    ushort4v wv = *(const ushort4v*)(W4 + c * 256 + lane * 4);
    acc[c] = hf[0] * bf2f(wv[0]) + hf[1] * bf2f(wv[1]) +
             hf[2] * bf2f(wv[2]) + hf[3] * bf2f(wv[3]);
  }
  #pragma unroll
  for (int c = 0; c < 10; ++c) {
    #pragma unroll
    for (int off = 32; off > 0; off >>= 1) acc[c] += __shfl_xor(acc[c], off);
  }
  if (lane < 10) {
    float v = 0.f;
    #pragma unroll
    for (int c = 0; c < 10; ++c)
      if (lane == c) v = acc[c];
    out[(size_t)row * 10 + lane] = v * a4;
  }
}

// =====================================================================================
extern "C" void kernel_launch(void* const* d_in, const int* in_sizes, int n_in,
                              void* d_out, int out_size, void* d_ws, size_t ws_size,
                              hipStream_t stream) {
  const float* x  = (const float*)d_in[0];
  const float* w1 = (const float*)d_in[1];
  const float* w2 = (const float*)d_in[2];
  const float* w3 = (const float*)d_in[3];
  const float* w4 = (const float*)d_in[4];
  const float* g1 = (const float*)d_in[5];
  const float* b1 = (const float*)d_in[6];
  const float* g2 = (const float*)d_in[7];
  const float* b2 = (const float*)d_in[8];
  const float* g3 = (const float*)d_in[9];
  const float* b3 = (const float*)d_in[10];
  float* out = (float*)d_out;

  // workspace layout (127 MB total; xq region aliased for y2 after xq is dead)
  char* ws = (char*)d_ws;
  float* alphas   = (float*)(ws + 0);                    // 4 f32
  float* apart    = (float*)(ws + 256);                  // 4*64 f32
  float* psum     = (float*)(ws + 1536);                 // 64*1024 f32
  float* psq      = (float*)(ws + 1050112);
  float* SB       = (float*)(ws + 2098688);              // 2*1024 f32
  ushort_t* wq1   = (ushort_t*)(ws + 2106880);           // 1024x832
  ushort_t* wq2   = (ushort_t*)(ws + 3810816);           // 512x1024
  ushort_t* wq3   = (ushort_t*)(ws + 4859392);           // 256x512
  ushort_t* wq4   = (ushort_t*)(ws + 5121536);           // 10x256
  ushort_t* xq    = (ushort_t*)(ws + 5126656);           // 32768x832 (54.5 MB)
  ushort_t* y2    = xq;                                  // alias: xq dead after GEMM1
  ushort_t* y3    = (ushort_t*)(ws + 5126656 + 33554432);
  ushort_t* y1    = (ushort_t*)(ws + 59652608);          // 32768x1024 (67 MB)

  dim3 blk(256);

  k_abs_partial<<<dim3(64, 4), blk, 0, stream>>>(w1, w2, w3, w4, apart);
  k_alpha_fin<<<1, blk, 0, stream>>>(apart, alphas);
  k_quantize<<<dim3(512, 4), blk, 0, stream>>>(w1, w2, w3, w4, wq1, wq2, wq3, wq4, alphas);
  k_convert_x<<<13312, blk, 0, stream>>>(x, xq);

  // layer 1: 32768 x 1024, K = 832 (padded); 2048 blocks, nbx = 8
  k_gemm_bt<<<2048, blk, 0, stream>>>(xq, wq1, y1, alphas, 0, 1024, 832, 3);
  k_bn_stats<1024><<<64, blk, 0, stream>>>(y1, psum, psq);
  k_bn_fin<<<4, blk, 0, stream>>>(psum, psq, g1, b1, 1024, SB);
  k_bn_norm<<<16384, blk, 0, stream>>>(y1, SB, 1024);

  // layer 2: 32768 x 512, K = 1024; 1024 blocks, nbx = 4
  k_gemm_bt<<<1024, blk, 0, stream>>>(y1, wq2, y2, alphas, 1, 512, 1024, 2);
  k_bn_stats<512><<<64, blk, 0, stream>>>(y2, psum, psq);
  k_bn_fin<<<2, blk, 0, stream>>>(psum, psq, g2, b2, 512, SB);
  k_bn_norm<<<8192, blk, 0, stream>>>(y2, SB, 512);

  // layer 3: 32768 x 256, K = 512; 512 blocks, nbx = 2
  k_gemm_bt<<<512, blk, 0, stream>>>(y2, wq3, y3, alphas, 2, 256, 512, 1);
  k_bn_stats<256><<<64, blk, 0, stream>>>(y3, psum, psq);
  k_bn_fin<<<1, blk, 0, stream>>>(psum, psq, g3, b3, 256, SB);
  // layer-3 normalize+ReLU fused into k_final

  // layer 4: 32768 x 10, K = 256 (memory-bound GEMV, BN3+ReLU fused)
  k_final<<<8192, blk, 0, stream>>>(y3, wq4, alphas, SB, out);
}